// Round 7
// baseline (1084.475 us; speedup 1.0000x reference)
//
#include <hip/hip_runtime.h>
#include <stdint.h>

#define DIM 128

static inline int cdiv(long a, long b) { return (int)((a + b - 1) / b); }

__device__ __forceinline__ unsigned short f2bf(float f) {
  unsigned int x = __float_as_uint(f);
  x = x + 0x7fffu + ((x >> 16) & 1u);   // RNE; values finite
  return (unsigned short)(x >> 16);
}
__device__ __forceinline__ float bflo(unsigned int u) {
  return __uint_as_float(u << 16);
}
__device__ __forceinline__ float bfhi(unsigned int u) {
  return __uint_as_float(u & 0xffff0000u);
}
__device__ __forceinline__ unsigned int packbf(float lo, float hi) {
  return ((unsigned int)f2bf(hi) << 16) | (unsigned int)f2bf(lo);
}

// ---- convert int64/int32 edge_index to int32 AND count degrees in one pass ----
__global__ __launch_bounds__(256) void convert_count_kernel(
    const int* __restrict__ raw, int* __restrict__ out, int* __restrict__ cnt,
    int E, long nnz) {
  bool is64;
  {
    int l = threadIdx.x & 63;
    int v = raw[2 * l + 1];
    unsigned long long m = __ballot(v == 0);
    is64 = (m == ~0ull);
  }
  long i = blockIdx.x * 256L + threadIdx.x;
  if (i < 2 * nnz) {
    int v = is64 ? raw[2 * i] : raw[i];
    out[i] = v;
    if (i < nnz) atomicAdd(&cnt[E + v], 1);   // src half -> node degree
    else         atomicAdd(&cnt[v], 1);       // edg half -> edge size
  }
}

// ---- 3-kernel exclusive scan of cnt[0..M) into P[0..M], P[M]=total ----
__global__ __launch_bounds__(256) void scanA_kernel(
    const int* __restrict__ cnt, int* __restrict__ P, int* __restrict__ BS, int M) {
  __shared__ int lds[256];
  int t = threadIdx.x;
  long base = blockIdx.x * 1024L;
  int v[4], ts = 0;
#pragma unroll
  for (int j = 0; j < 4; ++j) {
    long i = base + t * 4 + j;
    v[j] = (i < M) ? cnt[i] : 0;
    ts += v[j];
  }
  lds[t] = ts;
  __syncthreads();
  for (int off = 1; off < 256; off <<= 1) {
    int x = (t >= off) ? lds[t - off] : 0;
    __syncthreads();
    lds[t] += x;
    __syncthreads();
  }
  int run = lds[t] - ts;
#pragma unroll
  for (int j = 0; j < 4; ++j) {
    long i = base + t * 4 + j;
    if (i < M) P[i] = run;
    run += v[j];
  }
  if (t == 255) BS[blockIdx.x] = lds[255];
}

__global__ void scanB_kernel(int* __restrict__ BS, int* __restrict__ P,
                             int nblocks, int M) {
  if (threadIdx.x == 0) {
    int run = 0;
    for (int i = 0; i < nblocks; ++i) { int x = BS[i]; BS[i] = run; run += x; }
    P[M] = run;
  }
}

__global__ __launch_bounds__(256) void scanC_kernel(
    int* __restrict__ P, const int* __restrict__ BS, int M) {
  long i = blockIdx.x * 256L + threadIdx.x;
  if (i < M) P[i] += BS[i >> 10];
}

__global__ __launch_bounds__(256) void fill_adj_kernel(
    const int* __restrict__ src, const int* __restrict__ edg,
    const int* __restrict__ P, int* __restrict__ cnt,
    int* __restrict__ adj_e, int* __restrict__ adj_n, int E, int nnz) {
  int g = blockIdx.x * 256 + threadIdx.x;
  if (g < nnz) {
    int e = edg[g], s = src[g];
    int pe = P[e] + atomicAdd(&cnt[e], 1);
    adj_e[pe] = s;
    int pn = P[E + s] - nnz + atomicAdd(&cnt[E + s], 1);
    adj_n[pn] = e;
  }
}

// Wp = diag(a) @ W ; rvec = d @ W
__global__ void prep_w_kernel(const float* __restrict__ W,
                              const float* __restrict__ aff_a,
                              const float* __restrict__ aff_d,
                              float* __restrict__ Wp, float* __restrict__ rvec,
                              int has_aff) {
  int j = threadIdx.x;
  float racc = 0.0f;
  for (int c = 0; c < DIM; ++c) {
    float w = W[c * DIM + j];
    float a = has_aff ? aff_a[c] : 1.0f;
    float d = has_aff ? aff_d[c] : 0.0f;
    Wp[c * DIM + j] = a * w;
    racc = fmaf(d, w, racc);
  }
  rvec[j] = racc;
}

// ag[e][:] = Binv_e * sum X rows (fp32 input, layer 1).
// 32 lanes/edge (float4), 8 slots/block, unroll 4.
__global__ __launch_bounds__(256) void edge_gather_f32_kernel(
    const float* __restrict__ X, const int* __restrict__ P,
    const int* __restrict__ adj_e, float* __restrict__ ag, int E) {
  int slot = threadIdx.x >> 5;
  int l = threadIdx.x & 31;
  int e = blockIdx.x * 8 + slot;
  if (e >= E) return;
  int p0 = P[e], p1 = P[e + 1];
  const float4* X4 = (const float4*)X;
  float4 acc = {0.f, 0.f, 0.f, 0.f};
  int k = p0;
  for (; k + 3 < p1; k += 4) {
    int n0 = adj_e[k], n1 = adj_e[k + 1], n2 = adj_e[k + 2], n3 = adj_e[k + 3];
    float4 a0 = X4[(size_t)n0 * 32 + l];
    float4 a1 = X4[(size_t)n1 * 32 + l];
    float4 a2 = X4[(size_t)n2 * 32 + l];
    float4 a3 = X4[(size_t)n3 * 32 + l];
    acc.x += (a0.x + a1.x) + (a2.x + a3.x);
    acc.y += (a0.y + a1.y) + (a2.y + a3.y);
    acc.z += (a0.z + a1.z) + (a2.z + a3.z);
    acc.w += (a0.w + a1.w) + (a2.w + a3.w);
  }
  for (; k < p1; ++k) {
    float4 a0 = X4[(size_t)adj_e[k] * 32 + l];
    acc.x += a0.x; acc.y += a0.y; acc.z += a0.z; acc.w += a0.w;
  }
  float binv = (p1 > p0) ? 1.0f / (float)(p1 - p0) : 0.0f;
  acc.x *= binv; acc.y *= binv; acc.z *= binv; acc.w *= binv;
  ((float4*)ag)[(size_t)e * 32 + l] = acc;
}

// ag[e][:] = Binv_e * sum z rows (bf16 input, layers 2-3).
// 16 lanes/edge, lane l reads the 16B uint4 chunk l of each 256B row; unroll 4.
__global__ __launch_bounds__(256) void edge_gather_bf16_kernel(
    const unsigned short* __restrict__ Z, const int* __restrict__ P,
    const int* __restrict__ adj_e, float* __restrict__ ag, int E) {
  int slot = threadIdx.x >> 4;
  int l = threadIdx.x & 15;
  int e = blockIdx.x * 16 + slot;
  if (e >= E) return;
  int p0 = P[e], p1 = P[e + 1];
  const uint4* Z4 = (const uint4*)Z;
  float a[8];
#pragma unroll
  for (int j = 0; j < 8; ++j) a[j] = 0.f;
  int k = p0;
  for (; k + 3 < p1; k += 4) {
    int n0 = adj_e[k], n1 = adj_e[k + 1], n2 = adj_e[k + 2], n3 = adj_e[k + 3];
    uint4 q0 = Z4[(size_t)n0 * 16 + l];
    uint4 q1 = Z4[(size_t)n1 * 16 + l];
    uint4 q2 = Z4[(size_t)n2 * 16 + l];
    uint4 q3 = Z4[(size_t)n3 * 16 + l];
    a[0] += (bflo(q0.x) + bflo(q1.x)) + (bflo(q2.x) + bflo(q3.x));
    a[1] += (bfhi(q0.x) + bfhi(q1.x)) + (bfhi(q2.x) + bfhi(q3.x));
    a[2] += (bflo(q0.y) + bflo(q1.y)) + (bflo(q2.y) + bflo(q3.y));
    a[3] += (bfhi(q0.y) + bfhi(q1.y)) + (bfhi(q2.y) + bfhi(q3.y));
    a[4] += (bflo(q0.z) + bflo(q1.z)) + (bflo(q2.z) + bflo(q3.z));
    a[5] += (bfhi(q0.z) + bfhi(q1.z)) + (bfhi(q2.z) + bfhi(q3.z));
    a[6] += (bflo(q0.w) + bflo(q1.w)) + (bflo(q2.w) + bflo(q3.w));
    a[7] += (bfhi(q0.w) + bfhi(q1.w)) + (bfhi(q2.w) + bfhi(q3.w));
  }
  for (; k < p1; ++k) {
    uint4 q0 = Z4[(size_t)adj_e[k] * 16 + l];
    a[0] += bflo(q0.x); a[1] += bfhi(q0.x);
    a[2] += bflo(q0.y); a[3] += bfhi(q0.y);
    a[4] += bflo(q0.z); a[5] += bfhi(q0.z);
    a[6] += bflo(q0.w); a[7] += bfhi(q0.w);
  }
  float binv = (p1 > p0) ? 1.0f / (float)(p1 - p0) : 0.0f;
  float4* o = (float4*)ag + (size_t)e * 32 + l * 2;
  o[0] = (float4){a[0] * binv, a[1] * binv, a[2] * binv, a[3] * binv};
  o[1] = (float4){a[4] * binv, a[5] * binv, a[6] * binv, a[7] * binv};
}

// ef[E x 128](bf16) = ag(fp32) @ Wp + rvec, zeroed for empty edges.
__global__ __launch_bounds__(256) void gemm128_kernel(
    const float* __restrict__ X, const float* __restrict__ Wp,
    const float* __restrict__ rvec, const int* __restrict__ Pdeg,
    unsigned short* __restrict__ Y, int nrows) {
  __shared__ float sW[32 * DIM];
  __shared__ float sX[DIM * 36];
  const int t = threadIdx.x;
  const int row0 = blockIdx.x * DIM;
  const int tx = t & 15, ty = t >> 4;
  const int col0 = tx * 8, lr0 = ty * 8;
  float acc[8][8];
#pragma unroll
  for (int i = 0; i < 8; ++i)
#pragma unroll
    for (int j = 0; j < 8; ++j) acc[i][j] = 0.0f;

  for (int kc = 0; kc < 4; ++kc) {
    __syncthreads();
    {
      const float4* W4 = (const float4*)(Wp + kc * 32 * DIM);
      float4* sW4 = (float4*)sW;
#pragma unroll
      for (int i = 0; i < 4; ++i) sW4[t + i * 256] = W4[t + i * 256];
    }
#pragma unroll
    for (int i = 0; i < 4; ++i) {
      int q = t + i * 256;
      int rr = q >> 3, kq = q & 7;
      int gr = row0 + rr; if (gr >= nrows) gr = nrows - 1;
      float4 v = *(const float4*)&X[(size_t)gr * DIM + kc * 32 + kq * 4];
      *(float4*)&sX[rr * 36 + kq * 4] = v;
    }
    __syncthreads();
    for (int kk = 0; kk < 32; ++kk) {
      float4 w0 = *(const float4*)&sW[kk * DIM + col0];
      float4 w1 = *(const float4*)&sW[kk * DIM + col0 + 4];
      float wv[8] = {w0.x, w0.y, w0.z, w0.w, w1.x, w1.y, w1.z, w1.w};
      float xv[8];
#pragma unroll
      for (int i = 0; i < 8; ++i) xv[i] = sX[(lr0 + i) * 36 + kk];
#pragma unroll
      for (int i = 0; i < 8; ++i)
#pragma unroll
        for (int j = 0; j < 8; ++j) acc[i][j] = fmaf(xv[i], wv[j], acc[i][j]);
    }
  }
  float4 r0 = *(const float4*)&rvec[col0];
  float4 r1 = *(const float4*)&rvec[col0 + 4];
  float rv[8] = {r0.x, r0.y, r0.z, r0.w, r1.x, r1.y, r1.z, r1.w};
#pragma unroll
  for (int i = 0; i < 8; ++i) {
    int gr = row0 + lr0 + i;
    if (gr < nrows) {
      float nz = (Pdeg[gr + 1] > Pdeg[gr]) ? 1.0f : 0.0f;  // empty edge -> 0
      float v[8];
#pragma unroll
      for (int j = 0; j < 8; ++j) v[j] = (acc[i][j] + rv[j]) * nz;
      uint4 o;
      o.x = packbf(v[0], v[1]); o.y = packbf(v[2], v[3]);
      o.z = packbf(v[4], v[5]); o.w = packbf(v[6], v[7]);
      ((uint4*)Y)[(size_t)gr * 16 + tx] = o;
    }
  }
}

// z[i][:](bf16) = relu(Dinv_i * sum ef rows + b), fused BN stats.
// 16 lanes/node (uint4 = 8 channels each), 16 slots/block, unroll 4.
__global__ __launch_bounds__(256) void node_gather_kernel(
    const unsigned short* __restrict__ ef, const int* __restrict__ P,
    const int* __restrict__ adj_n, const float* __restrict__ b,
    unsigned short* __restrict__ z, float* __restrict__ sum,
    float* __restrict__ sumsq, int E, int N, int nnz) {
  __shared__ float lsum[DIM], lsumsq[DIM];
  int t = threadIdx.x;
  if (t < DIM) { lsum[t] = 0.f; lsumsq[t] = 0.f; }
  __syncthreads();
  int slot = t >> 4;
  int l = t & 15;
  int i = blockIdx.x * 16 + slot;
  const uint4* ef4 = (const uint4*)ef;
  float a[8];
#pragma unroll
  for (int j = 0; j < 8; ++j) a[j] = 0.f;
  int p0 = 0, p1 = 0;
  if (i < N) { p0 = P[E + i] - nnz; p1 = P[E + i + 1] - nnz; }
  int k = p0;
  for (; k + 3 < p1; k += 4) {
    int e0 = adj_n[k], e1 = adj_n[k + 1], e2 = adj_n[k + 2], e3 = adj_n[k + 3];
    uint4 q0 = ef4[(size_t)e0 * 16 + l];
    uint4 q1 = ef4[(size_t)e1 * 16 + l];
    uint4 q2 = ef4[(size_t)e2 * 16 + l];
    uint4 q3 = ef4[(size_t)e3 * 16 + l];
    a[0] += (bflo(q0.x) + bflo(q1.x)) + (bflo(q2.x) + bflo(q3.x));
    a[1] += (bfhi(q0.x) + bfhi(q1.x)) + (bfhi(q2.x) + bfhi(q3.x));
    a[2] += (bflo(q0.y) + bflo(q1.y)) + (bflo(q2.y) + bflo(q3.y));
    a[3] += (bfhi(q0.y) + bfhi(q1.y)) + (bfhi(q2.y) + bfhi(q3.y));
    a[4] += (bflo(q0.z) + bflo(q1.z)) + (bflo(q2.z) + bflo(q3.z));
    a[5] += (bfhi(q0.z) + bfhi(q1.z)) + (bfhi(q2.z) + bfhi(q3.z));
    a[6] += (bflo(q0.w) + bflo(q1.w)) + (bflo(q2.w) + bflo(q3.w));
    a[7] += (bfhi(q0.w) + bfhi(q1.w)) + (bfhi(q2.w) + bfhi(q3.w));
  }
  for (; k < p1; ++k) {
    uint4 q0 = ef4[(size_t)adj_n[k] * 16 + l];
    a[0] += bflo(q0.x); a[1] += bfhi(q0.x);
    a[2] += bflo(q0.y); a[3] += bfhi(q0.y);
    a[4] += bflo(q0.z); a[5] += bfhi(q0.z);
    a[6] += bflo(q0.w); a[7] += bfhi(q0.w);
  }
  float s1[8], s2[8];
#pragma unroll
  for (int j = 0; j < 8; ++j) { s1[j] = 0.f; s2[j] = 0.f; }
  if (i < N) {
    float dinv = (p1 > p0) ? 1.0f / (float)(p1 - p0) : 0.0f;
    const float4* b4 = (const float4*)b + l * 2;
    float4 bc0 = b4[0], bc1 = b4[1];
    float bc[8] = {bc0.x, bc0.y, bc0.z, bc0.w, bc1.x, bc1.y, bc1.z, bc1.w};
    float v[8];
#pragma unroll
    for (int j = 0; j < 8; ++j) {
      v[j] = fmaxf(fmaf(dinv, a[j], bc[j]), 0.f);
      s1[j] = v[j];
      s2[j] = v[j] * v[j];
    }
    uint4 o;
    o.x = packbf(v[0], v[1]); o.y = packbf(v[2], v[3]);
    o.z = packbf(v[4], v[5]); o.w = packbf(v[6], v[7]);
    ((uint4*)z)[(size_t)i * 16 + l] = o;
  }
  // reduce the 4 slots within each wave (lanes stride-16 share channels)
#pragma unroll
  for (int off = 16; off < 64; off <<= 1) {
#pragma unroll
    for (int j = 0; j < 8; ++j) {
      s1[j] += __shfl_down(s1[j], off);
      s2[j] += __shfl_down(s2[j], off);
    }
  }
  if ((t & 63) < 16) {
#pragma unroll
    for (int j = 0; j < 8; ++j) {
      atomicAdd(&lsum[l * 8 + j], s1[j]);
      atomicAdd(&lsumsq[l * 8 + j], s2[j]);
    }
  }
  __syncthreads();
  if (t < DIM) {
    atomicAdd(&sum[t], lsum[t]);
    atomicAdd(&sumsq[t], lsumsq[t]);
  }
}

// aff_a = g*rsqrt(var+eps); aff_d = beta - mu*aff_a
__global__ void finalize_bn_kernel(const float* __restrict__ sum,
                                   const float* __restrict__ sumsq,
                                   const float* __restrict__ g,
                                   const float* __restrict__ beta,
                                   float* __restrict__ aff_a, float* __restrict__ aff_d,
                                   int n) {
  int c = threadIdx.x;
  float inv_n = 1.0f / (float)n;
  float mu = sum[c] * inv_n;
  float var = fmaf(sumsq[c], inv_n, -mu * mu);
  float a = g[c] * rsqrtf(var + 1e-5f);
  aff_a[c] = a;
  aff_d[c] = fmaf(-mu, a, beta[c]);
}

// out(fp32) = aff_a * z(bf16) + aff_d; 8 channels per thread
__global__ __launch_bounds__(256) void apply_affine_kernel(
    const unsigned short* __restrict__ zin, const float* __restrict__ aff_a,
    const float* __restrict__ aff_d, float* __restrict__ out, long total8) {
  long i = blockIdx.x * 256L + threadIdx.x;
  if (i >= total8) return;
  int c16 = (int)(i & 15);          // 16 uint4-chunks per 128-ch row
  const float4* a4 = (const float4*)aff_a + c16 * 2;
  const float4* d4 = (const float4*)aff_d + c16 * 2;
  float4 a0 = a4[0], a1 = a4[1], d0 = d4[0], d1 = d4[1];
  uint4 q = ((const uint4*)zin)[i];
  float4 o0, o1;
  o0.x = fmaf(a0.x, bflo(q.x), d0.x);
  o0.y = fmaf(a0.y, bfhi(q.x), d0.y);
  o0.z = fmaf(a0.z, bflo(q.y), d0.z);
  o0.w = fmaf(a0.w, bfhi(q.y), d0.w);
  o1.x = fmaf(a1.x, bflo(q.z), d1.x);
  o1.y = fmaf(a1.y, bfhi(q.z), d1.y);
  o1.z = fmaf(a1.z, bflo(q.w), d1.z);
  o1.w = fmaf(a1.w, bfhi(q.w), d1.w);
  ((float4*)out)[i * 2]     = o0;
  ((float4*)out)[i * 2 + 1] = o1;
}

extern "C" void kernel_launch(void* const* d_in, const int* in_sizes, int n_in,
                              void* d_out, int out_size, void* d_ws, size_t ws_size,
                              hipStream_t stream) {
  const int NNZv = in_sizes[0] / 2;
  const int Nv   = in_sizes[1] / DIM;
  const int Ev   = in_sizes[2] / DIM;
  const int* eidx_raw = (const int*)d_in[0];
  const float* node_attr = (const float*)d_in[1];

  // ---- workspace layout (~52 MB) ----
  float* agbuf = (float*)d_ws;                 // E*128 f32 (10.2 MB)
  float* Wp    = agbuf + (size_t)Ev * DIM;     // 128*128
  float* rvec  = Wp + DIM * DIM;               // 128
  float* sums  = rvec + 128;                   // 128
  float* sumsq = sums + 128;                   // 128
  float* aff_a = sumsq + 128;                  // 128
  float* aff_d = aff_a + 128;                  // 128
  unsigned short* efbuf = (unsigned short*)(aff_d + 128);   // E*128 bf16 (5.1 MB)
  unsigned short* zbuf  = efbuf + (size_t)Ev * DIM;         // N*128 bf16 (25.6 MB)
  int* src   = (int*)(zbuf + (size_t)Nv * DIM);  // NNZ
  int* edg   = src + NNZv;                       // NNZ
  int* P     = edg + NNZv;                       // E+N+1
  int* BS    = P + (Ev + Nv + 1);                // <=256
  int* cnt   = BS + 256;                         // E+N
  int* adj_e = cnt + (Ev + Nv);                  // NNZ
  int* adj_n = adj_e + NNZv;                     // NNZ

  const int M = Ev + Nv;
  const int nbA = cdiv(M, 1024);

  hipMemsetAsync(cnt, 0, (size_t)M * 4, stream);
  convert_count_kernel<<<cdiv(2L * NNZv, 256), 256, 0, stream>>>(
      eidx_raw, src, cnt, Ev, NNZv);
  scanA_kernel<<<nbA, 256, 0, stream>>>(cnt, P, BS, M);
  scanB_kernel<<<1, 64, 0, stream>>>(BS, P, nbA, M);
  scanC_kernel<<<cdiv(M, 256), 256, 0, stream>>>(P, BS, M);
  hipMemsetAsync(cnt, 0, (size_t)M * 4, stream);
  fill_adj_kernel<<<cdiv(NNZv, 256), 256, 0, stream>>>(src, edg, P, cnt, adj_e, adj_n, Ev, NNZv);

  for (int l = 0; l < 3; ++l) {
    const float* W    = (const float*)d_in[3 + l * 4];
    const float* b    = (const float*)d_in[4 + l * 4];
    const float* g    = (const float*)d_in[5 + l * 4];
    const float* beta = (const float*)d_in[6 + l * 4];

    prep_w_kernel<<<1, 128, 0, stream>>>(W, aff_a, aff_d, Wp, rvec, l > 0 ? 1 : 0);
    if (l == 0)
      edge_gather_f32_kernel<<<cdiv(Ev, 8), 256, 0, stream>>>(node_attr, P, adj_e, agbuf, Ev);
    else
      edge_gather_bf16_kernel<<<cdiv(Ev, 16), 256, 0, stream>>>(zbuf, P, adj_e, agbuf, Ev);
    gemm128_kernel<<<cdiv(Ev, DIM), 256, 0, stream>>>(agbuf, Wp, rvec, P, efbuf, Ev);
    hipMemsetAsync(sums, 0, 256 * 4, stream);
    node_gather_kernel<<<cdiv(Nv, 16), 256, 0, stream>>>(efbuf, P, adj_n, b, zbuf,
                                                         sums, sumsq, Ev, Nv, NNZv);
    finalize_bn_kernel<<<1, 128, 0, stream>>>(sums, sumsq, g, beta, aff_a, aff_d, Nv);
  }
  apply_affine_kernel<<<cdiv((long)Nv * DIM / 8, 256), 256, 0, stream>>>(
      zbuf, aff_a, aff_d, (float*)d_out, (long)Nv * DIM / 8);
}